// Round 4
// baseline (551.081 us; speedup 1.0000x reference)
//
#include <hip/hip_runtime.h>

typedef unsigned short ushort_t;
typedef float f32x4 __attribute__((ext_vector_type(4)));
typedef _Float16 f16x8 __attribute__((ext_vector_type(8)));
typedef short s16x8 __attribute__((ext_vector_type(8)));

#define NB 8
#define QL 256
#define HID 4096
#define NH 32
#define HD 128

__device__ __forceinline__ _Float16 f2h(float f) { return (_Float16)f; }
__device__ __forceinline__ ushort_t h2u(_Float16 h) {
  union { _Float16 h; ushort_t u; } x; x.h = h; return x.u;
}
__device__ __forceinline__ float u2f(ushort_t u) {
  union { _Float16 h; ushort_t u; } x; x.u = u; return (float)x.h;
}

#define MFMA16H(a, b, c) __builtin_amdgcn_mfma_f32_16x16x32_f16((a), (b), (c), 0, 0, 0)
#define AS1 __attribute__((address_space(1)))
#define AS3 __attribute__((address_space(3)))

// ---------------------------------------------------------------------------
// fp32 -> fp16 convert
// ---------------------------------------------------------------------------
__global__ __launch_bounds__(256)
void conv_h(const float* __restrict__ s, ushort_t* __restrict__ d, int n8) {
  for (int i = blockIdx.x * blockDim.x + threadIdx.x; i < n8;
       i += gridDim.x * blockDim.x) {
    const float* sp = s + (size_t)i * 8;
    ushort_t t[8];
#pragma unroll
    for (int j = 0; j < 8; ++j) t[j] = h2u(f2h(sp[j]));
    *(s16x8*)(d + (size_t)i * 8) = *(s16x8*)t;
  }
}

// ---------------------------------------------------------------------------
// 256x256-tile 8-wave GEMM, BK=32, 4-deep LDS ring (128 KiB), counted vmcnt,
// T2 both-sides swizzle, T5 setprio. C = A[M][K] * B[N][K]^T (+bias).
// Requires: M%256==0, N%256==0, K%32==0, K/32 >= 8, (K/32)%4==0, grid%8==0.
// Grid 1D: wg -> (m-tile = wg&7, n-tile = wg>>3); M fixed at 2048 (8 m-tiles).
// ---------------------------------------------------------------------------
#define VM8 asm volatile("s_waitcnt vmcnt(8)" ::: "memory")
#define VM4 asm volatile("s_waitcnt vmcnt(4)" ::: "memory")
#define VM0 asm volatile("s_waitcnt vmcnt(0)" ::: "memory")
#define VMNONE

template<int ADD_BIAS>
__global__ __launch_bounds__(512, 2)
void gemm8p(const ushort_t* __restrict__ A, const ushort_t* __restrict__ Bm,
            const float* __restrict__ bias, ushort_t* __restrict__ Ch,
            int N, int K) {
  extern __shared__ ushort_t lds[];  // 4 bufs x (A 16KB + B 16KB) = 128 KiB
  const int nwg = gridDim.x;
  const int bid = blockIdx.x;
  const int wg = (bid & 7) * (nwg >> 3) + (bid >> 3);  // T1 bijective swizzle
  const int tile_m = (wg & 7) << 8;
  const int tile_n = (wg >> 3) << 8;
  const int tid = threadIdx.x;
  const int w = tid >> 6, l = tid & 63;
  const int l16 = l & 15, lg = l >> 4;
  const int wm = w >> 2, wn = w & 3;

  // staging: per-lane pre-swizzled global source (inverse of read swizzle)
  const int srow = w * 16 + (l >> 2);                   // 0..127 within half
  const int scol = ((l & 3) ^ ((l >> 2) & 3)) << 3;     // swizzled k-offset
  const ushort_t* gA = A + (size_t)(tile_m + srow) * K + scol;
  const ushort_t* gB = Bm + (size_t)(tile_n + srow) * K + scol;
  const size_t hstep = (size_t)128 * K;
  const int ldst_w = w * 512;  // wave's element offset within an 8KB half

  // read-side swizzle: element offset adj (byte: lg*16 ^ ((row&3)<<4))
  const int sw2 = ((lg * 16) ^ ((l16 & 3) << 4)) >> 1;

#define STG(buf, mat, half, jt)                                               \
  __builtin_amdgcn_global_load_lds(                                          \
      (const AS1 void*)(((mat) ? gB : gA) + (half) * hstep +                 \
                        (size_t)(jt) * 32),                                  \
      (AS3 void*)&lds[(buf) * 16384 + (mat) * 8192 + (half) * 4096 + ldst_w],\
      16, 0, 0)

  f32x4 acc[2][4][4];  // [qm][mf][nf]
#pragma unroll
  for (int q = 0; q < 2; ++q)
#pragma unroll
    for (int m = 0; m < 4; ++m)
#pragma unroll
      for (int n = 0; n < 4; ++n) acc[q][m][n] = (f32x4){0.f, 0.f, 0.f, 0.f};

#define LOADFRAGS(buf, qm)                                                    \
  _Pragma("unroll") for (int mf = 0; mf < 4; ++mf)                            \
      fa[mf] = *(const f16x8*)&lds[(buf) * 16384 +                            \
                                   (wm * 128 + (qm) * 64 + mf * 16 + l16) *   \
                                       32 + sw2];                             \
  _Pragma("unroll") for (int nf = 0; nf < 4; ++nf)                            \
      fb[nf] = *(const f16x8*)&lds[(buf) * 16384 + 8192 +                     \
                                   (wn * 64 + nf * 16 + l16) * 32 + sw2];

#define MFMAS(qm)                                                             \
  _Pragma("unroll") for (int mf = 0; mf < 4; ++mf)                            \
  _Pragma("unroll") for (int nf = 0; nf < 4; ++nf)                            \
      acc[qm][mf][nf] = MFMA16H(fa[mf], fb[nf], acc[qm][mf][nf])

#define PHASE(buf, qm, STGCODE, VMW)                                          \
  do {                                                                        \
    f16x8 fa[4], fb[4];                                                       \
    LOADFRAGS(buf, qm);                                                       \
    STGCODE;                                                                  \
    VMW;                                                                      \
    __builtin_amdgcn_s_barrier();                                             \
    asm volatile("s_waitcnt lgkmcnt(0)" ::: "memory");                        \
    __builtin_amdgcn_sched_barrier(0);                                        \
    __builtin_amdgcn_s_setprio(1);                                            \
    MFMAS(qm);                                                                \
    __builtin_amdgcn_s_setprio(0);                                            \
    __builtin_amdgcn_s_barrier();                                             \
  } while (0)

#define STG_A(jb, jt) STG(((jb) + 3) & 3, 0, 0, jt); STG(((jb) + 3) & 3, 0, 1, jt)
#define STG_B(jb, jt) STG(((jb) + 3) & 3, 1, 0, jt); STG(((jb) + 3) & 3, 1, 1, jt)

#define KTILE_S(j, jb, VMW2)                                                  \
  PHASE(jb, 0, STG_A(jb, (j) + 3), VMNONE);                                   \
  PHASE(jb, 1, STG_B(jb, (j) + 3), VMW2)

#define KTILE_N(j, jb, VMW2)                                                  \
  PHASE(jb, 0, VMNONE, VMNONE);                                               \
  PHASE(jb, 1, VMNONE, VMW2)

  const int NT = K >> 5;  // K/32

  // prologue: stage K-tiles 0,1,2; wait tile 0 resident (1,2 in flight)
  STG(0, 0, 0, 0); STG(0, 0, 1, 0); STG(0, 1, 0, 0); STG(0, 1, 1, 0);
  STG(1, 0, 0, 1); STG(1, 0, 1, 1); STG(1, 1, 0, 1); STG(1, 1, 1, 1);
  STG(2, 0, 0, 2); STG(2, 0, 1, 2); STG(2, 1, 0, 2); STG(2, 1, 1, 2);
  VM8;
  __builtin_amdgcn_s_barrier();

  int j = 0;
  for (; j + 4 < NT; j += 4) {
    KTILE_S(j, 0, VM8);
    KTILE_S(j + 1, 1, VM8);
    KTILE_S(j + 2, 2, VM8);
    KTILE_S(j + 3, 3, VM8);
  }
  // j == NT-4 here
  KTILE_S(j, 0, VM8);       // stages tile NT-1
  KTILE_N(j + 1, 1, VM4);
  KTILE_N(j + 2, 2, VM0);
  KTILE_N(j + 3, 3, VMNONE);

  // epilogue: C/D layout col=l16, row=lg*4+rr
#pragma unroll
  for (int qm = 0; qm < 2; ++qm)
#pragma unroll
    for (int nf = 0; nf < 4; ++nf) {
      const int col = tile_n + wn * 64 + nf * 16 + l16;
      const float bi = ADD_BIAS ? bias[col] : 0.f;
#pragma unroll
      for (int mf = 0; mf < 4; ++mf) {
        const int row0 = tile_m + wm * 128 + qm * 64 + mf * 16 + lg * 4;
#pragma unroll
        for (int rr = 0; rr < 4; ++rr)
          Ch[(size_t)(row0 + rr) * N + col] =
              h2u(f2h(acc[qm][mf][nf][rr] + bi));
      }
    }
#undef STG
#undef LOADFRAGS
#undef MFMAS
#undef PHASE
#undef STG_A
#undef STG_B
#undef KTILE_S
#undef KTILE_N
}

// ---------------------------------------------------------------------------
// m97-style 128x128 GEMM (kept for proj: only 128 blocks at 256^2 tile).
// OUT_F32: write float C.
// ---------------------------------------------------------------------------
template<int ADD_BIAS, int OUT_F32>
__global__ __launch_bounds__(256, 3)
void gemm_bt(const ushort_t* __restrict__ A, const ushort_t* __restrict__ Bm,
             const float* __restrict__ bias, ushort_t* __restrict__ Ch,
             float* __restrict__ Cf, int N, int K) {
  const int nwg = gridDim.x;
  const int bid = blockIdx.x;
  const int wg = (bid & 7) * (nwg >> 3) + (bid >> 3);
  const int tile_m = (wg & 15) * 128;
  const int tile_n = (wg >> 4) * 128;

  __shared__ ushort_t As[128 * 32];
  __shared__ ushort_t Bs[128 * 32];
  const int tid = threadIdx.x;
  const int w = tid >> 6, l = tid & 63;
  const int l16 = l & 15, lg = l >> 4;
  const int wr = w >> 1, wc = w & 1;

  f32x4 acc[4][4];
#pragma unroll
  for (int m = 0; m < 4; ++m)
#pragma unroll
    for (int n = 0; n < 4; ++n) acc[m][n] = (f32x4){0.f, 0.f, 0.f, 0.f};

  const int lrow = l >> 2;
  const int lseg = l & 3;
  const size_t a_base = (size_t)(tile_m + (w * 2) * 16 + lrow) * K + lseg * 8;
  const size_t b_base = (size_t)(tile_n + (w * 2) * 16 + lrow) * K + lseg * 8;

  for (int kt = 0; kt < K; kt += 32) {
#pragma unroll
    for (int i = 0; i < 2; ++i) {
      const int chunk = w * 2 + i;
      const ushort_t* ga = A + a_base + (size_t)i * 16 * K + kt;
      const ushort_t* gb = Bm + b_base + (size_t)i * 16 * K + kt;
      __builtin_amdgcn_global_load_lds(
          (const AS1 void*)ga, (AS3 void*)&As[chunk * 512], 16, 0, 0);
      __builtin_amdgcn_global_load_lds(
          (const AS1 void*)gb, (AS3 void*)&Bs[chunk * 512], 16, 0, 0);
    }
    __syncthreads();

    f16x8 af[4], bfr[4];
#pragma unroll
    for (int m = 0; m < 4; ++m)
      af[m] = *(const f16x8*)&As[(wr * 64 + m * 16 + l16) * 32 + lg * 8];
#pragma unroll
    for (int n = 0; n < 4; ++n)
      bfr[n] = *(const f16x8*)&Bs[(wc * 64 + n * 16 + l16) * 32 + lg * 8];
#pragma unroll
    for (int m = 0; m < 4; ++m)
#pragma unroll
      for (int n = 0; n < 4; ++n)
        acc[m][n] = MFMA16H(af[m], bfr[n], acc[m][n]);
    __syncthreads();
  }

#pragma unroll
  for (int n = 0; n < 4; ++n) {
    const int col = tile_n + wc * 64 + n * 16 + l16;
    const float bi = ADD_BIAS ? bias[col] : 0.0f;
#pragma unroll
    for (int m = 0; m < 4; ++m) {
      const int row0 = tile_m + wr * 64 + m * 16 + lg * 4;
#pragma unroll
      for (int r = 0; r < 4; ++r) {
        if (OUT_F32)
          Cf[(size_t)(row0 + r) * N + col] = acc[m][n][r] + bi;
        else
          Ch[(size_t)(row0 + r) * N + col] = h2u(f2h(acc[m][n][r] + bi));
      }
    }
  }
}

// ---------------------------------------------------------------------------
// RoPE + qkv split (fp16 in/out). q gets 1/sqrt(HD) folded in.
// ---------------------------------------------------------------------------
__global__ __launch_bounds__(256)
void rope_split(const ushort_t* __restrict__ qkv, const int* __restrict__ hist,
                ushort_t* __restrict__ q_r, ushort_t* __restrict__ k_r,
                ushort_t* __restrict__ v_r) {
  const int t = blockIdx.x;
  const int b = t >> 8, qq = t & 255;
  __shared__ float cs[64], sn[64];
  const int tid = threadIdx.x;
  if (tid < 64) {
    const float pos = (float)(hist[b] + qq);
    const float f = pos * __expf(-(float)tid * (9.210340371976184f / 64.0f));
    cs[tid] = cosf(f);
    sn[tid] = sinf(f);
  }
  __syncthreads();
  const ushort_t* src = qkv + (size_t)t * 12288;
  const float qscale = 0.08838834764831845f;
  for (int i = tid; i < NH * 64; i += 256) {
    const int h = i >> 6, j = i & 63;
    const float c = cs[j], s = sn[j];
    const size_t dst = ((size_t)(b * NH + h) * QL + qq) * HD;
    {
      const float x1 = u2f(src[h * HD + j]);
      const float x2 = u2f(src[h * HD + j + 64]);
      q_r[dst + j]      = h2u(f2h((x1 * c - x2 * s) * qscale));
      q_r[dst + j + 64] = h2u(f2h((x2 * c + x1 * s) * qscale));
    }
    {
      const float x1 = u2f(src[HID + h * HD + j]);
      const float x2 = u2f(src[HID + h * HD + j + 64]);
      k_r[dst + j]      = h2u(f2h(x1 * c - x2 * s));
      k_r[dst + j + 64] = h2u(f2h(x2 * c + x1 * s));
    }
    v_r[dst + j]      = src[2 * HID + h * HD + j];
    v_r[dst + j + 64] = src[2 * HID + h * HD + j + 64];
  }
}

// ---------------------------------------------------------------------------
// Flash attention over paged KV (caches fp32; fresh K/V fp16).
// ---------------------------------------------------------------------------
__global__ __launch_bounds__(512, 2)
void attn_fwd(const ushort_t* __restrict__ q_r, const ushort_t* __restrict__ k_r,
              const ushort_t* __restrict__ v_r,
              const float* __restrict__ k_cache, const float* __restrict__ v_cache,
              const int* __restrict__ hist, const int* __restrict__ bofs,
              ushort_t* __restrict__ attn_h) {
  const int bh = blockIdx.x;
  const int b = bh >> 5, h = bh & 31;
  const int hb = hist[b];

  __shared__ ushort_t K_lds[64 * 136];
  __shared__ ushort_t V_lds[128 * 72];
  __shared__ ushort_t P_lds[256 * 72];

  const int tid = threadIdx.x;
  const int w = tid >> 6, l = tid & 63;
  const int l16 = l & 15, lg = l >> 4;

  f16x8 qf[2][4];
#pragma unroll
  for (int m = 0; m < 2; ++m) {
    const int qrow = w * 32 + m * 16 + l16;
    const ushort_t* qp = q_r + ((size_t)(b * NH + h) * QL + qrow) * HD + lg * 8;
#pragma unroll
    for (int kd = 0; kd < 4; ++kd) qf[m][kd] = *(const f16x8*)(qp + kd * 32);
  }

  f32x4 o[2][8];
  float mr[2][4], sr[2][4];
#pragma unroll
  for (int m = 0; m < 2; ++m) {
#pragma unroll
    for (int d = 0; d < 8; ++d) o[m][d] = (f32x4){0.f, 0.f, 0.f, 0.f};
#pragma unroll
    for (int r = 0; r < 4; ++r) { mr[m][r] = -1e30f; sr[m][r] = 0.f; }
  }

  const int nt = (hb + QL + 63) >> 6;
  const int srow = tid >> 4;
  const int seg = tid & 15;

  for (int t = 0; t < nt; ++t) {
    const int kv0 = t << 6;
    __syncthreads();
#pragma unroll
    for (int p = 0; p < 2; ++p) {
      const int row = p * 32 + srow;
      const int kvg = kv0 + row;
      if (kvg < hb) {
        const int blk = bofs[b * 12 + t];
        const size_t base = ((size_t)blk * 64 + (kvg & 63)) * HID + h * HD;
        const float* kf = k_cache + base;
        const float* vf = v_cache + base;
        ushort_t tmp[8];
#pragma unroll
        for (int j = 0; j < 8; ++j) tmp[j] = h2u(f2h(kf[seg * 8 + j]));
        *(s16x8*)&K_lds[row * 136 + seg * 8] = *(s16x8*)tmp;
#pragma unroll
        for (int j = 0; j < 8; ++j) {
          const int d = seg + j * 16;
          V_lds[d * 72 + row] = h2u(f2h(vf[d]));
        }
      } else {
        int r2 = kvg - hb;
        if (r2 > QL - 1) r2 = QL - 1;
        const size_t base = ((size_t)(b * NH + h) * QL + r2) * HD;
        const ushort_t* kb = k_r + base;
        const ushort_t* vb = v_r + base;
        *(s16x8*)&K_lds[row * 136 + seg * 8] = *(const s16x8*)(kb + seg * 8);
#pragma unroll
        for (int j = 0; j < 8; ++j) {
          const int d = seg + j * 16;
          V_lds[d * 72 + row] = vb[d];
        }
      }
    }
    __syncthreads();

    f32x4 sa[2][4];
#pragma unroll
    for (int m = 0; m < 2; ++m)
#pragma unroll
      for (int n = 0; n < 4; ++n) sa[m][n] = (f32x4){0.f, 0.f, 0.f, 0.f};
#pragma unroll
    for (int kd = 0; kd < 4; ++kd) {
      f16x8 kf[4];
#pragma unroll
      for (int n = 0; n < 4; ++n)
        kf[n] = *(const f16x8*)&K_lds[(n * 16 + l16) * 136 + kd * 32 + lg * 8];
#pragma unroll
      for (int m = 0; m < 2; ++m)
#pragma unroll
        for (int n = 0; n < 4; ++n)
          sa[m][n] = MFMA16H(qf[m][kd], kf[n], sa[m][n]);
    }

#pragma unroll
    for (int m = 0; m < 2; ++m) {
#pragma unroll
      for (int n = 0; n < 4; ++n) {
        const int kvg = kv0 + n * 16 + l16;
#pragma unroll
        for (int r = 0; r < 4; ++r) {
          const int qg = hb + w * 32 + m * 16 + lg * 4 + r;
          if (kvg > qg) sa[m][n][r] = -1e30f;
        }
      }
      float tm[4], ts[4];
#pragma unroll
      for (int r = 0; r < 4; ++r)
        tm[r] = fmaxf(fmaxf(sa[m][0][r], sa[m][1][r]),
                      fmaxf(sa[m][2][r], sa[m][3][r]));
#pragma unroll
      for (int x = 1; x < 16; x <<= 1)
#pragma unroll
        for (int r = 0; r < 4; ++r)
          tm[r] = fmaxf(tm[r], __shfl_xor(tm[r], x, 16));
#pragma unroll
      for (int r = 0; r < 4; ++r) {
        const float nm = fmaxf(mr[m][r], tm[r]);
        const float corr = __expf(mr[m][r] - nm);
        mr[m][r] = nm;
        sr[m][r] *= corr;
#pragma unroll
        for (int d = 0; d < 8; ++d) o[m][d][r] *= corr;
        ts[r] = 0.f;
      }
#pragma unroll
      for (int n = 0; n < 4; ++n)
#pragma unroll
        for (int r = 0; r < 4; ++r) {
          const float p = __expf(sa[m][n][r] - mr[m][r]);
          sa[m][n][r] = p;
          ts[r] += p;
        }
#pragma unroll
      for (int x = 1; x < 16; x <<= 1)
#pragma unroll
        for (int r = 0; r < 4; ++r) ts[r] += __shfl_xor(ts[r], x, 16);
#pragma unroll
      for (int r = 0; r < 4; ++r) sr[m][r] += ts[r];
#pragma unroll
      for (int n = 0; n < 4; ++n)
#pragma unroll
        for (int r = 0; r < 4; ++r)
          P_lds[(w * 32 + m * 16 + lg * 4 + r) * 72 + n * 16 + l16] =
              h2u(f2h(sa[m][n][r]));
    }

#pragma unroll
    for (int ks = 0; ks < 2; ++ks) {
      f16x8 pa[2];
#pragma unroll
      for (int m = 0; m < 2; ++m)
        pa[m] = *(const f16x8*)&P_lds[(w * 32 + m * 16 + l16) * 72 + ks * 32 + lg * 8];
#pragma unroll
      for (int d = 0; d < 8; ++d) {
        const f16x8 vb =
            *(const f16x8*)&V_lds[(d * 16 + l16) * 72 + ks * 32 + lg * 8];
#pragma unroll
        for (int m = 0; m < 2; ++m) o[m][d] = MFMA16H(pa[m], vb, o[m][d]);
      }
    }
  }

#pragma unroll
  for (int m = 0; m < 2; ++m)
#pragma unroll
    for (int r = 0; r < 4; ++r) {
      const int qrow = w * 32 + m * 16 + lg * 4 + r;
      const float inv = 1.0f / sr[m][r];
      const size_t obase = ((size_t)(b * QL + qrow)) * HID + h * HD;
#pragma unroll
      for (int d = 0; d < 8; ++d)
        attn_h[obase + d * 16 + l16] = h2u(f2h(o[m][d][r] * inv));
    }
}

// ---------------------------------------------------------------------------
extern "C" void kernel_launch(void* const* d_in, const int* in_sizes, int n_in,
                              void* d_out, int out_size, void* d_ws,
                              size_t ws_size, hipStream_t stream) {
  const float* hidden   = (const float*)d_in[0];
  const float* c_attn_w = (const float*)d_in[1];
  const float* c_attn_b = (const float*)d_in[2];
  const float* c_proj_w = (const float*)d_in[3];
  const float* k_cache  = (const float*)d_in[4];
  const float* v_cache  = (const float*)d_in[5];
  const int* hist       = (const int*)d_in[6];
  const int* bofs       = (const int*)d_in[7];
  float* out = (float*)d_out;

  char* ws = (char*)d_ws;
  const size_t MB = 1ull << 20;
  ushort_t* w_attn_h = (ushort_t*)(ws);
  ushort_t* wproj_h  = (ushort_t*)(ws);
  ushort_t* qkv_h  = (ushort_t*)(ws + 100 * MB);
  ushort_t* attn_h = (ushort_t*)(ws + 100 * MB);
  ushort_t* q_r = (ushort_t*)(ws + 148 * MB);
  ushort_t* k_r = (ushort_t*)(ws + 164 * MB);
  ushort_t* v_r = (ushort_t*)(ws + 180 * MB);
  ushort_t* x_h = (ushort_t*)(ws + 196 * MB);

  conv_h<<<2048, 256, 0, stream>>>(hidden, x_h, 2048 * 4096 / 8);
  conv_h<<<2048, 256, 0, stream>>>(c_attn_w, w_attn_h, 12288 * 4096 / 8);
  // qkv = x @ c_attn_w^T + b : 8 m-tiles x 48 n-tiles = 384 blocks
  gemm8p<1><<<384, 512, 131072, stream>>>(x_h, w_attn_h, c_attn_b, qkv_h,
                                          12288, 4096);
  rope_split<<<2048, 256, 0, stream>>>(qkv_h, hist, q_r, k_r, v_r);
  conv_h<<<2048, 256, 0, stream>>>(c_proj_w, wproj_h, 4096 * 4096 / 8);
  attn_fwd<<<256, 512, 0, stream>>>(q_r, k_r, v_r, k_cache, v_cache, hist,
                                    bofs, attn_h);
  gemm_bt<0, 1><<<512, 256, 0, stream>>>(attn_h, wproj_h, nullptr, nullptr,
                                         out, 4096, 4096);
}

// Round 5
// 527.480 us; speedup vs baseline: 1.0447x; 1.0447x over previous
//
#include <hip/hip_runtime.h>

typedef unsigned short ushort_t;
typedef float f32x4 __attribute__((ext_vector_type(4)));
typedef _Float16 f16x8 __attribute__((ext_vector_type(8)));
typedef short s16x8 __attribute__((ext_vector_type(8)));

#define NB 8
#define QL 256
#define HID 4096
#define NH 32
#define HD 128

__device__ __forceinline__ _Float16 f2h(float f) { return (_Float16)f; }
__device__ __forceinline__ ushort_t h2u(_Float16 h) {
  union { _Float16 h; ushort_t u; } x; x.h = h; return x.u;
}
__device__ __forceinline__ float u2f(ushort_t u) {
  union { _Float16 h; ushort_t u; } x; x.u = u; return (float)x.h;
}

#define MFMA16H(a, b, c) __builtin_amdgcn_mfma_f32_16x16x32_f16((a), (b), (c), 0, 0, 0)
#define AS1 __attribute__((address_space(1)))
#define AS3 __attribute__((address_space(3)))

// ---------------------------------------------------------------------------
// fp32 -> fp16 convert
// ---------------------------------------------------------------------------
__global__ __launch_bounds__(256)
void conv_h(const float* __restrict__ s, ushort_t* __restrict__ d, int n8) {
  for (int i = blockIdx.x * blockDim.x + threadIdx.x; i < n8;
       i += gridDim.x * blockDim.x) {
    const float* sp = s + (size_t)i * 8;
    ushort_t t[8];
#pragma unroll
    for (int j = 0; j < 8; ++j) t[j] = h2u(f2h(sp[j]));
    *(s16x8*)(d + (size_t)i * 8) = *(s16x8*)t;
  }
}

// ---------------------------------------------------------------------------
// 256x128-tile GEMM, BK=32, 8 waves (4Mx2N, wave tile 64x64), ring-5 LDS
// (5 x 24KB = 120KB), counted vmcnt (6/3/0 tail), both-sides LDS swizzle,
// setprio around MFMA cluster, XCD-aware block swizzle.
// C[M][N] = A[M][K]*B[N][K]^T (+bias). M=2048 fixed (8 m-tiles).
// Grid: (M/256)*(N/128), %8==0. One phase per K-tile: 16 MFMA / 2 barriers.
// ---------------------------------------------------------------------------
#define VM6 asm volatile("s_waitcnt vmcnt(6)" ::: "memory")
#define VM3 asm volatile("s_waitcnt vmcnt(3)" ::: "memory")
#define VM0 asm volatile("s_waitcnt vmcnt(0)" ::: "memory")

template<int ADD_BIAS, int OUT_F32>
__global__ __launch_bounds__(512, 1)
void gemm5r(const ushort_t* __restrict__ A, const ushort_t* __restrict__ Bm,
            const float* __restrict__ bias, ushort_t* __restrict__ Ch,
            float* __restrict__ Cf, int N, int K) {
  extern __shared__ ushort_t lds[];  // 5 bufs x 12288 elements (24KB each)
  const int nwg = gridDim.x;
  const int bid = blockIdx.x;
  const int wg = (bid & 7) * (nwg >> 3) + (bid >> 3);  // XCD-bijective
  const int tile_m = (wg & 7) << 8;
  const int tile_n = (wg >> 3) << 7;
  const int tid = threadIdx.x;
  const int w = tid >> 6, l = tid & 63;
  const int l16 = l & 15, lg = l >> 4;
  const int wm = w >> 1, wn = w & 1;  // wave grid 4M x 2N

  // ---- stage: per-lane pre-swizzled global sources (3 loads/thread/tile) ----
  // A tile 256x32 (16KB): slots s = i*512 + w*64 + l; row=s>>2, seg=s&3
  // B tile 128x32 (8KB):  slot  s = w*64 + l
  size_t pa0, pa1, pbb;
  {
    const int s0 = w * 64 + l;
    const int s1 = 512 + w * 64 + l;
    const int r0 = s0 >> 2, g0 = s0 & 3;
    const int r1 = s1 >> 2, g1 = s1 & 3;
    pa0 = (size_t)(tile_m + r0) * K + ((g0 ^ (r0 & 3)) << 3);
    pa1 = (size_t)(tile_m + r1) * K + ((g1 ^ (r1 & 3)) << 3);
    pbb = (size_t)(tile_n + r0) * K + ((g0 ^ (r0 & 3)) << 3);
  }
  // wave-uniform LDS dest element offsets within a buf
  const int da0 = (w * 64) * 8;
  const int da1 = (512 + w * 64) * 8;
  const int dbb = 8192 + (w * 64) * 8;

  // ---- read-side swizzled fragment offsets ----
  int aoff[4], boff[4];
#pragma unroll
  for (int mf = 0; mf < 4; ++mf) {
    const int r = wm * 64 + mf * 16 + l16;
    aoff[mf] = r * 32 + ((lg ^ (r & 3)) << 3);
  }
#pragma unroll
  for (int nf = 0; nf < 4; ++nf) {
    const int r = wn * 64 + nf * 16 + l16;
    boff[nf] = 8192 + r * 32 + ((lg ^ (r & 3)) << 3);
  }

  f32x4 acc[4][4];
#pragma unroll
  for (int m = 0; m < 4; ++m)
#pragma unroll
    for (int n = 0; n < 4; ++n) acc[m][n] = (f32x4){0.f, 0.f, 0.f, 0.f};

#define STG3(bufel, jt)                                                       \
  do {                                                                        \
    __builtin_amdgcn_global_load_lds(                                         \
        (const AS1 void*)(A + pa0 + (size_t)(jt) * 32),                       \
        (AS3 void*)&lds[(bufel) + da0], 16, 0, 0);                            \
    __builtin_amdgcn_global_load_lds(                                         \
        (const AS1 void*)(A + pa1 + (size_t)(jt) * 32),                       \
        (AS3 void*)&lds[(bufel) + da1], 16, 0, 0);                            \
    __builtin_amdgcn_global_load_lds(                                         \
        (const AS1 void*)(Bm + pbb + (size_t)(jt) * 32),                      \
        (AS3 void*)&lds[(bufel) + dbb], 16, 0, 0);                            \
  } while (0)

  const int NT = K >> 5;

  // prologue: stage tiles 0,1,2 (9 loads); wait tile 0 (6 left in flight)
  STG3(0, 0);
  STG3(12288, 1);
  STG3(24576, 2);
  VM6;
  __builtin_amdgcn_s_barrier();

  int bufc = 0;          // compute buf element offset (tile j)
  int bufs = 3 * 12288;  // stage buf element offset (tile j+3)
  for (int j = 0; j < NT; ++j) {
    if (j + 3 < NT) STG3(bufs, j + 3);
    f16x8 fa[4], fb[4];
#pragma unroll
    for (int mf = 0; mf < 4; ++mf)
      fa[mf] = *(const f16x8*)&lds[bufc + aoff[mf]];
#pragma unroll
    for (int nf = 0; nf < 4; ++nf)
      fb[nf] = *(const f16x8*)&lds[bufc + boff[nf]];
    if (j <= NT - 4) VM6;
    else if (j == NT - 3) VM3;
    else if (j == NT - 2) VM0;
    __builtin_amdgcn_s_barrier();
    asm volatile("s_waitcnt lgkmcnt(0)" ::: "memory");
    __builtin_amdgcn_sched_barrier(0);
    __builtin_amdgcn_s_setprio(1);
#pragma unroll
    for (int mf = 0; mf < 4; ++mf)
#pragma unroll
      for (int nf = 0; nf < 4; ++nf)
        acc[mf][nf] = MFMA16H(fa[mf], fb[nf], acc[mf][nf]);
    __builtin_amdgcn_s_setprio(0);
    __builtin_amdgcn_s_barrier();
    bufc += 12288; if (bufc == 61440) bufc = 0;
    bufs += 12288; if (bufs == 61440) bufs = 0;
  }

  // epilogue: C/D layout col=l16, row=lg*4+rr
#pragma unroll
  for (int nf = 0; nf < 4; ++nf) {
    const int col = tile_n + wn * 64 + nf * 16 + l16;
    const float bi = ADD_BIAS ? bias[col] : 0.f;
#pragma unroll
    for (int mf = 0; mf < 4; ++mf) {
      const int row0 = tile_m + wm * 64 + mf * 16 + lg * 4;
#pragma unroll
      for (int rr = 0; rr < 4; ++rr) {
        if (OUT_F32)
          Cf[(size_t)(row0 + rr) * N + col] = acc[mf][nf][rr] + bi;
        else
          Ch[(size_t)(row0 + rr) * N + col] = h2u(f2h(acc[mf][nf][rr] + bi));
      }
    }
  }
#undef STG3
}

// ---------------------------------------------------------------------------
// RoPE + qkv split (fp16 in/out). q gets 1/sqrt(HD) folded in.
// ---------------------------------------------------------------------------
__global__ __launch_bounds__(256)
void rope_split(const ushort_t* __restrict__ qkv, const int* __restrict__ hist,
                ushort_t* __restrict__ q_r, ushort_t* __restrict__ k_r,
                ushort_t* __restrict__ v_r) {
  const int t = blockIdx.x;
  const int b = t >> 8, qq = t & 255;
  __shared__ float cs[64], sn[64];
  const int tid = threadIdx.x;
  if (tid < 64) {
    const float pos = (float)(hist[b] + qq);
    const float f = pos * __expf(-(float)tid * (9.210340371976184f / 64.0f));
    cs[tid] = cosf(f);
    sn[tid] = sinf(f);
  }
  __syncthreads();
  const ushort_t* src = qkv + (size_t)t * 12288;
  const float qscale = 0.08838834764831845f;
  for (int i = tid; i < NH * 64; i += 256) {
    const int h = i >> 6, j = i & 63;
    const float c = cs[j], s = sn[j];
    const size_t dst = ((size_t)(b * NH + h) * QL + qq) * HD;
    {
      const float x1 = u2f(src[h * HD + j]);
      const float x2 = u2f(src[h * HD + j + 64]);
      q_r[dst + j]      = h2u(f2h((x1 * c - x2 * s) * qscale));
      q_r[dst + j + 64] = h2u(f2h((x2 * c + x1 * s) * qscale));
    }
    {
      const float x1 = u2f(src[HID + h * HD + j]);
      const float x2 = u2f(src[HID + h * HD + j + 64]);
      k_r[dst + j]      = h2u(f2h(x1 * c - x2 * s));
      k_r[dst + j + 64] = h2u(f2h(x2 * c + x1 * s));
    }
    v_r[dst + j]      = src[2 * HID + h * HD + j];
    v_r[dst + j + 64] = src[2 * HID + h * HD + j + 64];
  }
}

// ---------------------------------------------------------------------------
// Flash attention over paged KV (caches fp32; fresh K/V fp16).
// ---------------------------------------------------------------------------
__global__ __launch_bounds__(512, 2)
void attn_fwd(const ushort_t* __restrict__ q_r, const ushort_t* __restrict__ k_r,
              const ushort_t* __restrict__ v_r,
              const float* __restrict__ k_cache, const float* __restrict__ v_cache,
              const int* __restrict__ hist, const int* __restrict__ bofs,
              ushort_t* __restrict__ attn_h) {
  const int bh = blockIdx.x;
  const int b = bh >> 5, h = bh & 31;
  const int hb = hist[b];

  __shared__ ushort_t K_lds[64 * 136];
  __shared__ ushort_t V_lds[128 * 72];
  __shared__ ushort_t P_lds[256 * 72];

  const int tid = threadIdx.x;
  const int w = tid >> 6, l = tid & 63;
  const int l16 = l & 15, lg = l >> 4;

  f16x8 qf[2][4];
#pragma unroll
  for (int m = 0; m < 2; ++m) {
    const int qrow = w * 32 + m * 16 + l16;
    const ushort_t* qp = q_r + ((size_t)(b * NH + h) * QL + qrow) * HD + lg * 8;
#pragma unroll
    for (int kd = 0; kd < 4; ++kd) qf[m][kd] = *(const f16x8*)(qp + kd * 32);
  }

  f32x4 o[2][8];
  float mr[2][4], sr[2][4];
#pragma unroll
  for (int m = 0; m < 2; ++m) {
#pragma unroll
    for (int d = 0; d < 8; ++d) o[m][d] = (f32x4){0.f, 0.f, 0.f, 0.f};
#pragma unroll
    for (int r = 0; r < 4; ++r) { mr[m][r] = -1e30f; sr[m][r] = 0.f; }
  }

  const int nt = (hb + QL + 63) >> 6;
  const int srow = tid >> 4;
  const int seg = tid & 15;

  for (int t = 0; t < nt; ++t) {
    const int kv0 = t << 6;
    __syncthreads();
#pragma unroll
    for (int p = 0; p < 2; ++p) {
      const int row = p * 32 + srow;
      const int kvg = kv0 + row;
      if (kvg < hb) {
        const int blk = bofs[b * 12 + t];
        const size_t base = ((size_t)blk * 64 + (kvg & 63)) * HID + h * HD;
        const float* kf = k_cache + base;
        const float* vf = v_cache + base;
        ushort_t tmp[8];
#pragma unroll
        for (int j = 0; j < 8; ++j) tmp[j] = h2u(f2h(kf[seg * 8 + j]));
        *(s16x8*)&K_lds[row * 136 + seg * 8] = *(s16x8*)tmp;
#pragma unroll
        for (int j = 0; j < 8; ++j) {
          const int d = seg + j * 16;
          V_lds[d * 72 + row] = h2u(f2h(vf[d]));
        }
      } else {
        int r2 = kvg - hb;
        if (r2 > QL - 1) r2 = QL - 1;
        const size_t base = ((size_t)(b * NH + h) * QL + r2) * HD;
        const ushort_t* kb = k_r + base;
        const ushort_t* vb = v_r + base;
        *(s16x8*)&K_lds[row * 136 + seg * 8] = *(const s16x8*)(kb + seg * 8);
#pragma unroll
        for (int j = 0; j < 8; ++j) {
          const int d = seg + j * 16;
          V_lds[d * 72 + row] = vb[d];
        }
      }
    }
    __syncthreads();

    f32x4 sa[2][4];
#pragma unroll
    for (int m = 0; m < 2; ++m)
#pragma unroll
      for (int n = 0; n < 4; ++n) sa[m][n] = (f32x4){0.f, 0.f, 0.f, 0.f};
#pragma unroll
    for (int kd = 0; kd < 4; ++kd) {
      f16x8 kf[4];
#pragma unroll
      for (int n = 0; n < 4; ++n)
        kf[n] = *(const f16x8*)&K_lds[(n * 16 + l16) * 136 + kd * 32 + lg * 8];
#pragma unroll
      for (int m = 0; m < 2; ++m)
#pragma unroll
        for (int n = 0; n < 4; ++n)
          sa[m][n] = MFMA16H(qf[m][kd], kf[n], sa[m][n]);
    }

#pragma unroll
    for (int m = 0; m < 2; ++m) {
#pragma unroll
      for (int n = 0; n < 4; ++n) {
        const int kvg = kv0 + n * 16 + l16;
#pragma unroll
        for (int r = 0; r < 4; ++r) {
          const int qg = hb + w * 32 + m * 16 + lg * 4 + r;
          if (kvg > qg) sa[m][n][r] = -1e30f;
        }
      }
      float tm[4], ts[4];
#pragma unroll
      for (int r = 0; r < 4; ++r)
        tm[r] = fmaxf(fmaxf(sa[m][0][r], sa[m][1][r]),
                      fmaxf(sa[m][2][r], sa[m][3][r]));
#pragma unroll
      for (int x = 1; x < 16; x <<= 1)
#pragma unroll
        for (int r = 0; r < 4; ++r)
          tm[r] = fmaxf(tm[r], __shfl_xor(tm[r], x, 16));
#pragma unroll
      for (int r = 0; r < 4; ++r) {
        const float nm = fmaxf(mr[m][r], tm[r]);
        const float corr = __expf(mr[m][r] - nm);
        mr[m][r] = nm;
        sr[m][r] *= corr;
#pragma unroll
        for (int d = 0; d < 8; ++d) o[m][d][r] *= corr;
        ts[r] = 0.f;
      }
#pragma unroll
      for (int n = 0; n < 4; ++n)
#pragma unroll
        for (int r = 0; r < 4; ++r) {
          const float p = __expf(sa[m][n][r] - mr[m][r]);
          sa[m][n][r] = p;
          ts[r] += p;
        }
#pragma unroll
      for (int x = 1; x < 16; x <<= 1)
#pragma unroll
        for (int r = 0; r < 4; ++r) ts[r] += __shfl_xor(ts[r], x, 16);
#pragma unroll
      for (int r = 0; r < 4; ++r) sr[m][r] += ts[r];
#pragma unroll
      for (int n = 0; n < 4; ++n)
#pragma unroll
        for (int r = 0; r < 4; ++r)
          P_lds[(w * 32 + m * 16 + lg * 4 + r) * 72 + n * 16 + l16] =
              h2u(f2h(sa[m][n][r]));
    }

#pragma unroll
    for (int ks = 0; ks < 2; ++ks) {
      f16x8 pa[2];
#pragma unroll
      for (int m = 0; m < 2; ++m)
        pa[m] = *(const f16x8*)&P_lds[(w * 32 + m * 16 + l16) * 72 + ks * 32 + lg * 8];
#pragma unroll
      for (int d = 0; d < 8; ++d) {
        const f16x8 vb =
            *(const f16x8*)&V_lds[(d * 16 + l16) * 72 + ks * 32 + lg * 8];
#pragma unroll
        for (int m = 0; m < 2; ++m) o[m][d] = MFMA16H(pa[m], vb, o[m][d]);
      }
    }
  }

#pragma unroll
  for (int m = 0; m < 2; ++m)
#pragma unroll
    for (int r = 0; r < 4; ++r) {
      const int qrow = w * 32 + m * 16 + lg * 4 + r;
      const float inv = 1.0f / sr[m][r];
      const size_t obase = ((size_t)(b * QL + qrow)) * HID + h * HD;
#pragma unroll
      for (int d = 0; d < 8; ++d)
        attn_h[obase + d * 16 + l16] = h2u(f2h(o[m][d][r] * inv));
    }
}

// ---------------------------------------------------------------------------
extern "C" void kernel_launch(void* const* d_in, const int* in_sizes, int n_in,
                              void* d_out, int out_size, void* d_ws,
                              size_t ws_size, hipStream_t stream) {
  const float* hidden   = (const float*)d_in[0];
  const float* c_attn_w = (const float*)d_in[1];
  const float* c_attn_b = (const float*)d_in[2];
  const float* c_proj_w = (const float*)d_in[3];
  const float* k_cache  = (const float*)d_in[4];
  const float* v_cache  = (const float*)d_in[5];
  const int* hist       = (const int*)d_in[6];
  const int* bofs       = (const int*)d_in[7];
  float* out = (float*)d_out;

  char* ws = (char*)d_ws;
  const size_t MB = 1ull << 20;
  ushort_t* w_attn_h = (ushort_t*)(ws);
  ushort_t* wproj_h  = (ushort_t*)(ws);
  ushort_t* qkv_h  = (ushort_t*)(ws + 100 * MB);
  ushort_t* attn_h = (ushort_t*)(ws + 100 * MB);
  ushort_t* q_r = (ushort_t*)(ws + 148 * MB);
  ushort_t* k_r = (ushort_t*)(ws + 164 * MB);
  ushort_t* v_r = (ushort_t*)(ws + 180 * MB);
  ushort_t* x_h = (ushort_t*)(ws + 196 * MB);

  conv_h<<<2048, 256, 0, stream>>>(hidden, x_h, 2048 * 4096 / 8);
  conv_h<<<2048, 256, 0, stream>>>(c_attn_w, w_attn_h, 12288 * 4096 / 8);
  // qkv = x @ c_attn_w^T + b : 8 m-tiles x 96 n-tiles = 768 blocks (3 rounds)
  gemm5r<1, 0><<<768, 512, 122880, stream>>>(x_h, w_attn_h, c_attn_b, qkv_h,
                                             nullptr, 12288, 4096);
  rope_split<<<2048, 256, 0, stream>>>(qkv_h, hist, q_r, k_r, v_r);
  conv_h<<<2048, 256, 0, stream>>>(c_proj_w, wproj_h, 4096 * 4096 / 8);
  attn_fwd<<<256, 512, 0, stream>>>(q_r, k_r, v_r, k_cache, v_cache, hist,
                                    bofs, attn_h);
  // out = attn @ c_proj_w^T : 8 x 32 = 256 blocks (1 round)
  gemm5r<0, 1><<<256, 512, 122880, stream>>>(attn_h, wproj_h, nullptr, nullptr,
                                             out, 4096, 4096);
}

// Round 6
// 455.066 us; speedup vs baseline: 1.2110x; 1.1591x over previous
//
#include <hip/hip_runtime.h>

typedef unsigned short ushort_t;
typedef float f32x4 __attribute__((ext_vector_type(4)));
typedef _Float16 f16x8 __attribute__((ext_vector_type(8)));
typedef short s16x8 __attribute__((ext_vector_type(8)));

#define NB 8
#define QL 256
#define HID 4096
#define NH 32
#define HD 128

__device__ __forceinline__ _Float16 f2h(float f) { return (_Float16)f; }
__device__ __forceinline__ ushort_t h2u(_Float16 h) {
  union { _Float16 h; ushort_t u; } x; x.h = h; return x.u;
}
__device__ __forceinline__ float u2f(ushort_t u) {
  union { _Float16 h; ushort_t u; } x; x.u = u; return (float)x.h;
}

#define MFMA16H(a, b, c) __builtin_amdgcn_mfma_f32_16x16x32_f16((a), (b), (c), 0, 0, 0)
#define AS1 __attribute__((address_space(1)))
#define AS3 __attribute__((address_space(3)))

// ---------------------------------------------------------------------------
// fp32 -> fp16, MFMA-native tiling: dst[mb][kb][lane][8],
// lane = (row&15) | (seg<<4), element = src[mb*16+row][kb*32+seg*8+j].
// 64 threads per tile; 256-thread blocks handle 4 tiles.
// ---------------------------------------------------------------------------
__global__ __launch_bounds__(256)
void conv_tile(const float* __restrict__ src, ushort_t* __restrict__ dst,
               int K, int ntiles) {
  const int tile = blockIdx.x * 4 + (threadIdx.x >> 6);
  if (tile >= ntiles) return;
  const int u = threadIdx.x & 63;
  const int row = u >> 2, seg = u & 3;  // seg fast -> 128B contiguous reads
  const int K32 = K >> 5;
  const int mb = tile / K32, kb = tile % K32;
  const float* sp = src + (size_t)(mb * 16 + row) * K + kb * 32 + seg * 8;
  ushort_t t[8];
#pragma unroll
  for (int j = 0; j < 8; ++j) t[j] = h2u(f2h(sp[j]));
  *(s16x8*)(dst + (size_t)tile * 512 + (((seg << 4) | row) * 8)) = *(s16x8*)t;
}

// fp16 linear -> MFMA-native tiling (for attn output)
__global__ __launch_bounds__(256)
void retile_h(const ushort_t* __restrict__ src, ushort_t* __restrict__ dst,
              int K, int ntiles) {
  const int tile = blockIdx.x * 4 + (threadIdx.x >> 6);
  if (tile >= ntiles) return;
  const int u = threadIdx.x & 63;
  const int row = u >> 2, seg = u & 3;
  const int K32 = K >> 5;
  const int mb = tile / K32, kb = tile % K32;
  const s16x8 v = *(const s16x8*)(src + (size_t)(mb * 16 + row) * K + kb * 32 + seg * 8);
  *(s16x8*)(dst + (size_t)tile * 512 + (((seg << 4) | row) * 8)) = v;
}

// ---------------------------------------------------------------------------
// Tiled-operand GEMM: C[M][N] = A*B^T (+bias), A_t/B_t in [rb][kb][lane][8].
// BM=256 BN=128 BK=32, 8 waves (4Mx2N, wave 64x64), ring-3 LDS 72KB
// (2 blocks/CU), 1 barrier + counted vmcnt(3) per K-tile, zero LDS conflicts
// by construction (all LDS ops are lane-contiguous 16B).
// NT = K/32 (template; NT%3==2 assumed, NT>=8). M=2048 fixed.
// ---------------------------------------------------------------------------
#define VM3 asm volatile("s_waitcnt vmcnt(3)" ::: "memory")
#define VM0 asm volatile("s_waitcnt vmcnt(0)" ::: "memory")
#define NOSTG

template<int ADD_BIAS, int OUT_F32, int NT>
__global__ __launch_bounds__(512, 4)
void gemm_t(const ushort_t* __restrict__ At, const ushort_t* __restrict__ Bt,
            const float* __restrict__ bias, ushort_t* __restrict__ Ch,
            float* __restrict__ Cf, int N) {
  static_assert(NT % 3 == 2 && NT >= 8, "tail assumes NT%3==2");
  extern __shared__ ushort_t lds[];  // 3 rings x (A 8192 + B 4096) elems = 72KB
  const int nwg = gridDim.x, bid = blockIdx.x;
  const int wg = (bid & 7) * (nwg >> 3) + (bid >> 3);  // XCD-bijective
  const int mi = wg & 7, ni = wg >> 3;
  const int tid = threadIdx.x, w = tid >> 6, l = tid & 63;
  const int l16 = l & 15, lg = l >> 4;
  const int wm = w >> 1, wn = w & 1;

  // stage sources: contiguous 1KB per wave-load, per-lane l*16B
  const ushort_t* sA0 = At + ((size_t)(mi * 16 + 2 * w) * NT) * 512 + l * 8;
  const ushort_t* sA1 = At + ((size_t)(mi * 16 + 2 * w + 1) * NT) * 512 + l * 8;
  const ushort_t* sB  = Bt + ((size_t)(ni * 8 + w) * NT) * 512 + l * 8;

  // fragment read offsets (lane-contiguous -> conflict-free)
  int aof[4], bof[4];
#pragma unroll
  for (int mf = 0; mf < 4; ++mf) aof[mf] = (wm * 4 + mf) * 512 + l * 8;
#pragma unroll
  for (int nf = 0; nf < 4; ++nf) bof[nf] = 8192 + (wn * 4 + nf) * 512 + l * 8;

  f32x4 acc[4][4];
#pragma unroll
  for (int m = 0; m < 4; ++m)
#pragma unroll
    for (int n = 0; n < 4; ++n) acc[m][n] = (f32x4){0.f, 0.f, 0.f, 0.f};

#define GLDS(srcp, dstofs)                                                    \
  __builtin_amdgcn_global_load_lds((const AS1 void*)(srcp),                   \
                                   (AS3 void*)&lds[dstofs], 16, 0, 0)
#define STG(R, J)                                                             \
  do {                                                                        \
    GLDS(sA0 + (size_t)(J) * 512, (R) * 12288 + (2 * w) * 512);               \
    GLDS(sA1 + (size_t)(J) * 512, (R) * 12288 + (2 * w + 1) * 512);           \
    GLDS(sB + (size_t)(J) * 512, (R) * 12288 + 8192 + w * 512);               \
  } while (0)

#define ITER(R, VMW, STGCODE)                                                 \
  do {                                                                        \
    VMW;                                                                      \
    __builtin_amdgcn_s_barrier();                                             \
    STGCODE;                                                                  \
    f16x8 fa[4], fb[4];                                                       \
    _Pragma("unroll") for (int mf = 0; mf < 4; ++mf)                          \
        fa[mf] = *(const f16x8*)&lds[(R) * 12288 + aof[mf]];                  \
    _Pragma("unroll") for (int nf = 0; nf < 4; ++nf)                          \
        fb[nf] = *(const f16x8*)&lds[(R) * 12288 + bof[nf]];                  \
    asm volatile("s_waitcnt lgkmcnt(0)" ::: "memory");                        \
    __builtin_amdgcn_sched_barrier(0);                                        \
    __builtin_amdgcn_s_setprio(1);                                            \
    _Pragma("unroll") for (int mf = 0; mf < 4; ++mf)                          \
    _Pragma("unroll") for (int nf = 0; nf < 4; ++nf)                          \
        acc[mf][nf] = MFMA16H(fa[mf], fb[nf], acc[mf][nf]);                   \
    __builtin_amdgcn_s_setprio(0);                                            \
  } while (0)

  STG(0, 0);
  STG(1, 1);
  for (int j = 0; j < NT - 2; j += 3) {
    ITER(0, VM3, STG(2, j + 2));
    ITER(1, VM3, STG(0, j + 3));
    ITER(2, VM3, STG(1, j + 4));
  }
  ITER(0, VM3, NOSTG);  // tile NT-2
  ITER(1, VM0, NOSTG);  // tile NT-1

  // epilogue: C/D layout col=l16, row=lg*4+rr
#pragma unroll
  for (int nf = 0; nf < 4; ++nf) {
    const int col = ni * 128 + wn * 64 + nf * 16 + l16;
    const float bi = ADD_BIAS ? bias[col] : 0.f;
#pragma unroll
    for (int mf = 0; mf < 4; ++mf) {
      const int row0 = mi * 256 + wm * 64 + mf * 16 + lg * 4;
#pragma unroll
      for (int rr = 0; rr < 4; ++rr) {
        if (OUT_F32)
          Cf[(size_t)(row0 + rr) * N + col] = acc[mf][nf][rr] + bi;
        else
          Ch[(size_t)(row0 + rr) * N + col] = h2u(f2h(acc[mf][nf][rr] + bi));
      }
    }
  }
#undef GLDS
#undef STG
#undef ITER
}

// ---------------------------------------------------------------------------
// RoPE + qkv split (fp16 in/out). q gets 1/sqrt(HD) folded in.
// ---------------------------------------------------------------------------
__global__ __launch_bounds__(256)
void rope_split(const ushort_t* __restrict__ qkv, const int* __restrict__ hist,
                ushort_t* __restrict__ q_r, ushort_t* __restrict__ k_r,
                ushort_t* __restrict__ v_r) {
  const int t = blockIdx.x;
  const int b = t >> 8, qq = t & 255;
  __shared__ float cs[64], sn[64];
  const int tid = threadIdx.x;
  if (tid < 64) {
    const float pos = (float)(hist[b] + qq);
    const float f = pos * __expf(-(float)tid * (9.210340371976184f / 64.0f));
    cs[tid] = cosf(f);
    sn[tid] = sinf(f);
  }
  __syncthreads();
  const ushort_t* src = qkv + (size_t)t * 12288;
  const float qscale = 0.08838834764831845f;
  for (int i = tid; i < NH * 64; i += 256) {
    const int h = i >> 6, j = i & 63;
    const float c = cs[j], s = sn[j];
    const size_t dst = ((size_t)(b * NH + h) * QL + qq) * HD;
    {
      const float x1 = u2f(src[h * HD + j]);
      const float x2 = u2f(src[h * HD + j + 64]);
      q_r[dst + j]      = h2u(f2h((x1 * c - x2 * s) * qscale));
      q_r[dst + j + 64] = h2u(f2h((x2 * c + x1 * s) * qscale));
    }
    {
      const float x1 = u2f(src[HID + h * HD + j]);
      const float x2 = u2f(src[HID + h * HD + j + 64]);
      k_r[dst + j]      = h2u(f2h(x1 * c - x2 * s));
      k_r[dst + j + 64] = h2u(f2h(x2 * c + x1 * s));
    }
    v_r[dst + j]      = src[2 * HID + h * HD + j];
    v_r[dst + j + 64] = src[2 * HID + h * HD + j + 64];
  }
}

// ---------------------------------------------------------------------------
// Flash attention over paged KV (caches fp32; fresh K/V fp16).
// ---------------------------------------------------------------------------
__global__ __launch_bounds__(512, 2)
void attn_fwd(const ushort_t* __restrict__ q_r, const ushort_t* __restrict__ k_r,
              const ushort_t* __restrict__ v_r,
              const float* __restrict__ k_cache, const float* __restrict__ v_cache,
              const int* __restrict__ hist, const int* __restrict__ bofs,
              ushort_t* __restrict__ attn_h) {
  const int bh = blockIdx.x;
  const int b = bh >> 5, h = bh & 31;
  const int hb = hist[b];

  __shared__ ushort_t K_lds[64 * 136];
  __shared__ ushort_t V_lds[128 * 72];
  __shared__ ushort_t P_lds[256 * 72];

  const int tid = threadIdx.x;
  const int w = tid >> 6, l = tid & 63;
  const int l16 = l & 15, lg = l >> 4;

  f16x8 qf[2][4];
#pragma unroll
  for (int m = 0; m < 2; ++m) {
    const int qrow = w * 32 + m * 16 + l16;
    const ushort_t* qp = q_r + ((size_t)(b * NH + h) * QL + qrow) * HD + lg * 8;
#pragma unroll
    for (int kd = 0; kd < 4; ++kd) qf[m][kd] = *(const f16x8*)(qp + kd * 32);
  }

  f32x4 o[2][8];
  float mr[2][4], sr[2][4];
#pragma unroll
  for (int m = 0; m < 2; ++m) {
#pragma unroll
    for (int d = 0; d < 8; ++d) o[m][d] = (f32x4){0.f, 0.f, 0.f, 0.f};
#pragma unroll
    for (int r = 0; r < 4; ++r) { mr[m][r] = -1e30f; sr[m][r] = 0.f; }
  }

  const int nt = (hb + QL + 63) >> 6;
  const int srow = tid >> 4;
  const int seg = tid & 15;

  for (int t = 0; t < nt; ++t) {
    const int kv0 = t << 6;
    __syncthreads();
#pragma unroll
    for (int p = 0; p < 2; ++p) {
      const int row = p * 32 + srow;
      const int kvg = kv0 + row;
      if (kvg < hb) {
        const int blk = bofs[b * 12 + t];
        const size_t base = ((size_t)blk * 64 + (kvg & 63)) * HID + h * HD;
        const float* kf = k_cache + base;
        const float* vf = v_cache + base;
        ushort_t tmp[8];
#pragma unroll
        for (int j = 0; j < 8; ++j) tmp[j] = h2u(f2h(kf[seg * 8 + j]));
        *(s16x8*)&K_lds[row * 136 + seg * 8] = *(s16x8*)tmp;
#pragma unroll
        for (int j = 0; j < 8; ++j) {
          const int d = seg + j * 16;
          V_lds[d * 72 + row] = h2u(f2h(vf[d]));
        }
      } else {
        int r2 = kvg - hb;
        if (r2 > QL - 1) r2 = QL - 1;
        const size_t base = ((size_t)(b * NH + h) * QL + r2) * HD;
        const ushort_t* kb = k_r + base;
        const ushort_t* vb = v_r + base;
        *(s16x8*)&K_lds[row * 136 + seg * 8] = *(const s16x8*)(kb + seg * 8);
#pragma unroll
        for (int j = 0; j < 8; ++j) {
          const int d = seg + j * 16;
          V_lds[d * 72 + row] = vb[d];
        }
      }
    }
    __syncthreads();

    f32x4 sa[2][4];
#pragma unroll
    for (int m = 0; m < 2; ++m)
#pragma unroll
      for (int n = 0; n < 4; ++n) sa[m][n] = (f32x4){0.f, 0.f, 0.f, 0.f};
#pragma unroll
    for (int kd = 0; kd < 4; ++kd) {
      f16x8 kf[4];
#pragma unroll
      for (int n = 0; n < 4; ++n)
        kf[n] = *(const f16x8*)&K_lds[(n * 16 + l16) * 136 + kd * 32 + lg * 8];
#pragma unroll
      for (int m = 0; m < 2; ++m)
#pragma unroll
        for (int n = 0; n < 4; ++n)
          sa[m][n] = MFMA16H(qf[m][kd], kf[n], sa[m][n]);
    }

#pragma unroll
    for (int m = 0; m < 2; ++m) {
#pragma unroll
      for (int n = 0; n < 4; ++n) {
        const int kvg = kv0 + n * 16 + l16;
#pragma unroll
        for (int r = 0; r < 4; ++r) {
          const int qg = hb + w * 32 + m * 16 + lg * 4 + r;
          if (kvg > qg) sa[m][n][r] = -1e30f;
        }
      }
      float tm[4], ts[4];
#pragma unroll
      for (int r = 0; r < 4; ++r)
        tm[r] = fmaxf(fmaxf(sa[m][0][r], sa[m][1][r]),
                      fmaxf(sa[m][2][r], sa[m][3][r]));
#pragma unroll
      for (int x = 1; x < 16; x <<= 1)
#pragma unroll
        for (int r = 0; r < 4; ++r)
          tm[r] = fmaxf(tm[r], __shfl_xor(tm[r], x, 16));
#pragma unroll
      for (int r = 0; r < 4; ++r) {
        const float nm = fmaxf(mr[m][r], tm[r]);
        const float corr = __expf(mr[m][r] - nm);
        mr[m][r] = nm;
        sr[m][r] *= corr;
#pragma unroll
        for (int d = 0; d < 8; ++d) o[m][d][r] *= corr;
        ts[r] = 0.f;
      }
#pragma unroll
      for (int n = 0; n < 4; ++n)
#pragma unroll
        for (int r = 0; r < 4; ++r) {
          const float p = __expf(sa[m][n][r] - mr[m][r]);
          sa[m][n][r] = p;
          ts[r] += p;
        }
#pragma unroll
      for (int x = 1; x < 16; x <<= 1)
#pragma unroll
        for (int r = 0; r < 4; ++r) ts[r] += __shfl_xor(ts[r], x, 16);
#pragma unroll
      for (int r = 0; r < 4; ++r) sr[m][r] += ts[r];
#pragma unroll
      for (int n = 0; n < 4; ++n)
#pragma unroll
        for (int r = 0; r < 4; ++r)
          P_lds[(w * 32 + m * 16 + lg * 4 + r) * 72 + n * 16 + l16] =
              h2u(f2h(sa[m][n][r]));
    }

#pragma unroll
    for (int ks = 0; ks < 2; ++ks) {
      f16x8 pa[2];
#pragma unroll
      for (int m = 0; m < 2; ++m)
        pa[m] = *(const f16x8*)&P_lds[(w * 32 + m * 16 + l16) * 72 + ks * 32 + lg * 8];
#pragma unroll
      for (int d = 0; d < 8; ++d) {
        const f16x8 vb =
            *(const f16x8*)&V_lds[(d * 16 + l16) * 72 + ks * 32 + lg * 8];
#pragma unroll
        for (int m = 0; m < 2; ++m) o[m][d] = MFMA16H(pa[m], vb, o[m][d]);
      }
    }
  }

#pragma unroll
  for (int m = 0; m < 2; ++m)
#pragma unroll
    for (int r = 0; r < 4; ++r) {
      const int qrow = w * 32 + m * 16 + lg * 4 + r;
      const float inv = 1.0f / sr[m][r];
      const size_t obase = ((size_t)(b * QL + qrow)) * HID + h * HD;
#pragma unroll
      for (int d = 0; d < 8; ++d)
        attn_h[obase + d * 16 + l16] = h2u(f2h(o[m][d][r] * inv));
    }
}

// ---------------------------------------------------------------------------
extern "C" void kernel_launch(void* const* d_in, const int* in_sizes, int n_in,
                              void* d_out, int out_size, void* d_ws,
                              size_t ws_size, hipStream_t stream) {
  const float* hidden   = (const float*)d_in[0];
  const float* c_attn_w = (const float*)d_in[1];
  const float* c_attn_b = (const float*)d_in[2];
  const float* c_proj_w = (const float*)d_in[3];
  const float* k_cache  = (const float*)d_in[4];
  const float* v_cache  = (const float*)d_in[5];
  const int* hist       = (const int*)d_in[6];
  const int* bofs       = (const int*)d_in[7];
  float* out = (float*)d_out;

  char* ws = (char*)d_ws;
  const size_t MB = 1ull << 20;
  ushort_t* w_attn_t = (ushort_t*)(ws);            // 96MB, phases 1-3
  ushort_t* wproj_t  = (ushort_t*)(ws);            // 32MB, phase 5+ (w_attn dead)
  ushort_t* qkv_h   = (ushort_t*)(ws + 100 * MB);  // 48MB, phases 3-4
  ushort_t* attn_h  = (ushort_t*)(ws + 100 * MB);  // alias, qkv dead after rope
  ushort_t* attn_t  = (ushort_t*)(ws + 116 * MB);  // 16MB tiled attn
  ushort_t* q_r = (ushort_t*)(ws + 148 * MB);
  ushort_t* k_r = (ushort_t*)(ws + 164 * MB);
  ushort_t* v_r = (ushort_t*)(ws + 180 * MB);
  ushort_t* x_t = (ushort_t*)(ws + 196 * MB);      // 16MB tiled x

  // 1) tile-convert inputs for qkv GEMM
  conv_tile<<<4096, 256, 0, stream>>>(hidden, x_t, 4096, 16384);
  conv_tile<<<24576, 256, 0, stream>>>(c_attn_w, w_attn_t, 4096, 98304);
  // 2) qkv = x @ c_attn_w^T + b : 8 x 96 = 768 blocks
  gemm_t<1, 0, 128><<<768, 512, 73728, stream>>>(x_t, w_attn_t, c_attn_b,
                                                 qkv_h, nullptr, 12288);
  // 3) rope + split
  rope_split<<<2048, 256, 0, stream>>>(qkv_h, hist, q_r, k_r, v_r);
  // 4) tile-convert proj weights (overwrites w_attn region; stream-ordered)
  conv_tile<<<8192, 256, 0, stream>>>(c_proj_w, wproj_t, 4096, 32768);
  // 5) attention -> attn_h (overwrites qkv region; qkv dead after rope)
  attn_fwd<<<256, 512, 0, stream>>>(q_r, k_r, v_r, k_cache, v_cache, hist,
                                    bofs, attn_h);
  // 6) re-tile attn for proj GEMM
  retile_h<<<4096, 256, 0, stream>>>(attn_h, attn_t, 4096, 16384);
  // 7) out = attn @ c_proj_w^T : 8 x 32 = 256 blocks
  gemm_t<0, 1, 128><<<256, 512, 73728, stream>>>(attn_t, wproj_t, nullptr,
                                                 nullptr, out, 4096);
}

// Round 7
// 412.007 us; speedup vs baseline: 1.3376x; 1.1045x over previous
//
#include <hip/hip_runtime.h>

typedef unsigned short ushort_t;
typedef float f32x4 __attribute__((ext_vector_type(4)));
typedef _Float16 f16x8 __attribute__((ext_vector_type(8)));
typedef short s16x8 __attribute__((ext_vector_type(8)));

#define NB 8
#define QL 256
#define HID 4096
#define NH 32
#define HD 128

__device__ __forceinline__ _Float16 f2h(float f) { return (_Float16)f; }
__device__ __forceinline__ ushort_t h2u(_Float16 h) {
  union { _Float16 h; ushort_t u; } x; x.h = h; return x.u;
}
__device__ __forceinline__ float u2f(ushort_t u) {
  union { _Float16 h; ushort_t u; } x; x.u = u; return (float)x.h;
}

#define MFMA16H(a, b, c) __builtin_amdgcn_mfma_f32_16x16x32_f16((a), (b), (c), 0, 0, 0)
#define AS1 __attribute__((address_space(1)))
#define AS3 __attribute__((address_space(3)))

// ---------------------------------------------------------------------------
// fp32 -> fp16, MFMA-native tiling: dst[mb][kb][lane][8],
// lane = (row&15) | (seg<<4), element = src[mb*16+row][kb*32+seg*8+j].
// ---------------------------------------------------------------------------
__global__ __launch_bounds__(256)
void conv_tile(const float* __restrict__ src, ushort_t* __restrict__ dst,
               int K, int ntiles) {
  const int tile = blockIdx.x * 4 + (threadIdx.x >> 6);
  if (tile >= ntiles) return;
  const int u = threadIdx.x & 63;
  const int row = u >> 2, seg = u & 3;
  const int K32 = K >> 5;
  const int mb = tile / K32, kb = tile % K32;
  const float* sp = src + (size_t)(mb * 16 + row) * K + kb * 32 + seg * 8;
  ushort_t t[8];
#pragma unroll
  for (int j = 0; j < 8; ++j) t[j] = h2u(f2h(sp[j]));
  *(s16x8*)(dst + (size_t)tile * 512 + (((seg << 4) | row) * 8)) = *(s16x8*)t;
}

// ---------------------------------------------------------------------------
// Tiled-operand GEMM: C[M][N] = A*B^T (+bias), A_t/B_t in [rb][kb][lane][8].
// BM=256 BN=128 BK=32, 8 waves (4Mx2N, wave 64x64), ring-3 LDS 72KB
// (2 blocks/CU), 1 barrier + counted vmcnt(3) per K-tile, zero LDS conflicts.
// ---------------------------------------------------------------------------
#define VM3 asm volatile("s_waitcnt vmcnt(3)" ::: "memory")
#define VM0 asm volatile("s_waitcnt vmcnt(0)" ::: "memory")
#define NOSTG

template<int ADD_BIAS, int OUT_F32, int NT>
__global__ __launch_bounds__(512, 4)
void gemm_t(const ushort_t* __restrict__ At, const ushort_t* __restrict__ Bt,
            const float* __restrict__ bias, ushort_t* __restrict__ Ch,
            float* __restrict__ Cf, int N) {
  static_assert(NT % 3 == 2 && NT >= 8, "tail assumes NT%3==2");
  extern __shared__ ushort_t lds[];  // 3 rings x (A 8192 + B 4096) elems
  const int nwg = gridDim.x, bid = blockIdx.x;
  const int wg = (bid & 7) * (nwg >> 3) + (bid >> 3);  // XCD-bijective
  const int mi = wg & 7, ni = wg >> 3;
  const int tid = threadIdx.x, w = tid >> 6, l = tid & 63;
  const int l16 = l & 15, lg = l >> 4;
  const int wm = w >> 1, wn = w & 1;

  const ushort_t* sA0 = At + ((size_t)(mi * 16 + 2 * w) * NT) * 512 + l * 8;
  const ushort_t* sA1 = At + ((size_t)(mi * 16 + 2 * w + 1) * NT) * 512 + l * 8;
  const ushort_t* sB  = Bt + ((size_t)(ni * 8 + w) * NT) * 512 + l * 8;

  int aof[4], bof[4];
#pragma unroll
  for (int mf = 0; mf < 4; ++mf) aof[mf] = (wm * 4 + mf) * 512 + l * 8;
#pragma unroll
  for (int nf = 0; nf < 4; ++nf) bof[nf] = 8192 + (wn * 4 + nf) * 512 + l * 8;

  f32x4 acc[4][4];
#pragma unroll
  for (int m = 0; m < 4; ++m)
#pragma unroll
    for (int n = 0; n < 4; ++n) acc[m][n] = (f32x4){0.f, 0.f, 0.f, 0.f};

#define GLDS(srcp, dstofs)                                                    \
  __builtin_amdgcn_global_load_lds((const AS1 void*)(srcp),                   \
                                   (AS3 void*)&lds[dstofs], 16, 0, 0)
#define STG(R, J)                                                             \
  do {                                                                        \
    GLDS(sA0 + (size_t)(J) * 512, (R) * 12288 + (2 * w) * 512);               \
    GLDS(sA1 + (size_t)(J) * 512, (R) * 12288 + (2 * w + 1) * 512);           \
    GLDS(sB + (size_t)(J) * 512, (R) * 12288 + 8192 + w * 512);               \
  } while (0)

#define ITER(R, VMW, STGCODE)                                                 \
  do {                                                                        \
    VMW;                                                                      \
    __builtin_amdgcn_s_barrier();                                             \
    STGCODE;                                                                  \
    f16x8 fa[4], fb[4];                                                       \
    _Pragma("unroll") for (int mf = 0; mf < 4; ++mf)                          \
        fa[mf] = *(const f16x8*)&lds[(R) * 12288 + aof[mf]];                  \
    _Pragma("unroll") for (int nf = 0; nf < 4; ++nf)                          \
        fb[nf] = *(const f16x8*)&lds[(R) * 12288 + bof[nf]];                  \
    asm volatile("s_waitcnt lgkmcnt(0)" ::: "memory");                        \
    __builtin_amdgcn_sched_barrier(0);                                        \
    __builtin_amdgcn_s_setprio(1);                                            \
    _Pragma("unroll") for (int mf = 0; mf < 4; ++mf)                          \
    _Pragma("unroll") for (int nf = 0; nf < 4; ++nf)                          \
        acc[mf][nf] = MFMA16H(fa[mf], fb[nf], acc[mf][nf]);                   \
    __builtin_amdgcn_s_setprio(0);                                            \
  } while (0)

  STG(0, 0);
  STG(1, 1);
  for (int j = 0; j < NT - 2; j += 3) {
    ITER(0, VM3, STG(2, j + 2));
    ITER(1, VM3, STG(0, j + 3));
    ITER(2, VM3, STG(1, j + 4));
  }
  ITER(0, VM3, NOSTG);
  ITER(1, VM0, NOSTG);

#pragma unroll
  for (int nf = 0; nf < 4; ++nf) {
    const int col = ni * 128 + wn * 64 + nf * 16 + l16;
    const float bi = ADD_BIAS ? bias[col] : 0.f;
#pragma unroll
    for (int mf = 0; mf < 4; ++mf) {
      const int row0 = mi * 256 + wm * 64 + mf * 16 + lg * 4;
#pragma unroll
      for (int rr = 0; rr < 4; ++rr) {
        if (OUT_F32)
          Cf[(size_t)(row0 + rr) * N + col] = acc[mf][nf][rr] + bi;
        else
          Ch[(size_t)(row0 + rr) * N + col] = h2u(f2h(acc[mf][nf][rr] + bi));
      }
    }
  }
#undef GLDS
#undef STG
#undef ITER
}

// ---------------------------------------------------------------------------
// RoPE in place on qkv (q cols 0..4095 with 1/sqrt(HD) folded; k cols
// 4096..8191; v untouched). One block per token; safe under graph replay
// because the GEMM regenerates qkv every call.
// ---------------------------------------------------------------------------
__global__ __launch_bounds__(256)
void rope_inplace(ushort_t* __restrict__ qkv, const int* __restrict__ hist) {
  const int t = blockIdx.x;
  const int b = t >> 8, qq = t & 255;
  __shared__ float cs[64], sn[64];
  const int tid = threadIdx.x;
  if (tid < 64) {
    const float pos = (float)(hist[b] + qq);
    const float f = pos * __expf(-(float)tid * (9.210340371976184f / 64.0f));
    cs[tid] = cosf(f);
    sn[tid] = sinf(f);
  }
  __syncthreads();
  ushort_t* row = qkv + (size_t)t * 12288;
  const int h = tid >> 3;        // 0..31
  const int j0 = (tid & 7) * 8;  // 0..56
  const float qscale = 0.08838834764831845f;
  float c[8], s[8];
#pragma unroll
  for (int j = 0; j < 8; ++j) { c[j] = cs[j0 + j]; s[j] = sn[j0 + j]; }
  // q
  {
    ushort_t* p1 = row + h * HD + j0;
    ushort_t* p2 = p1 + 64;
    s16x8 a = *(s16x8*)p1, bb = *(s16x8*)p2;
    ushort_t o1[8], o2[8];
#pragma unroll
    for (int j = 0; j < 8; ++j) {
      const float x1 = u2f((ushort_t)a[j]), x2 = u2f((ushort_t)bb[j]);
      o1[j] = h2u(f2h((x1 * c[j] - x2 * s[j]) * qscale));
      o2[j] = h2u(f2h((x2 * c[j] + x1 * s[j]) * qscale));
    }
    *(s16x8*)p1 = *(s16x8*)o1;
    *(s16x8*)p2 = *(s16x8*)o2;
  }
  // k
  {
    ushort_t* p1 = row + HID + h * HD + j0;
    ushort_t* p2 = p1 + 64;
    s16x8 a = *(s16x8*)p1, bb = *(s16x8*)p2;
    ushort_t o1[8], o2[8];
#pragma unroll
    for (int j = 0; j < 8; ++j) {
      const float x1 = u2f((ushort_t)a[j]), x2 = u2f((ushort_t)bb[j]);
      o1[j] = h2u(f2h(x1 * c[j] - x2 * s[j]));
      o2[j] = h2u(f2h(x2 * c[j] + x1 * s[j]));
    }
    *(s16x8*)p1 = *(s16x8*)o1;
    *(s16x8*)p2 = *(s16x8*)o2;
  }
}

// ---------------------------------------------------------------------------
// Flash attention over paged KV. Q/K/V fresh rows read from qkv (roped);
// caches fp32. Output written directly in MFMA-tiled layout (attn_t).
// ---------------------------------------------------------------------------
__global__ __launch_bounds__(512, 2)
void attn_fwd(const ushort_t* __restrict__ qkv,
              const float* __restrict__ k_cache, const float* __restrict__ v_cache,
              const int* __restrict__ hist, const int* __restrict__ bofs,
              ushort_t* __restrict__ attn_t) {
  const int bh = blockIdx.x;
  const int b = bh >> 5, h = bh & 31;
  const int hb = hist[b];

  __shared__ ushort_t K_lds[64 * 136];
  __shared__ ushort_t V_lds[128 * 72];
  __shared__ ushort_t P_lds[256 * 72];

  const int tid = threadIdx.x;
  const int w = tid >> 6, l = tid & 63;
  const int l16 = l & 15, lg = l >> 4;

  f16x8 qf[2][4];
#pragma unroll
  for (int m = 0; m < 2; ++m) {
    const int qrow = w * 32 + m * 16 + l16;
    const ushort_t* qp = qkv + (size_t)(b * QL + qrow) * 12288 + h * HD + lg * 8;
#pragma unroll
    for (int kd = 0; kd < 4; ++kd) qf[m][kd] = *(const f16x8*)(qp + kd * 32);
  }

  f32x4 o[2][8];
  float mr[2][4], sr[2][4];
#pragma unroll
  for (int m = 0; m < 2; ++m) {
#pragma unroll
    for (int d = 0; d < 8; ++d) o[m][d] = (f32x4){0.f, 0.f, 0.f, 0.f};
#pragma unroll
    for (int r = 0; r < 4; ++r) { mr[m][r] = -1e30f; sr[m][r] = 0.f; }
  }

  const int nt = (hb + QL + 63) >> 6;
  const int srow = tid >> 4;
  const int seg = tid & 15;

  for (int t = 0; t < nt; ++t) {
    const int kv0 = t << 6;
    __syncthreads();
#pragma unroll
    for (int p = 0; p < 2; ++p) {
      const int row = p * 32 + srow;
      const int kvg = kv0 + row;
      if (kvg < hb) {
        const int blk = bofs[b * 12 + t];
        const size_t base = ((size_t)blk * 64 + (kvg & 63)) * HID + h * HD;
        const float* kf = k_cache + base;
        const float* vf = v_cache + base;
        ushort_t tmp[8];
#pragma unroll
        for (int j = 0; j < 8; ++j) tmp[j] = h2u(f2h(kf[seg * 8 + j]));
        *(s16x8*)&K_lds[row * 136 + seg * 8] = *(s16x8*)tmp;
#pragma unroll
        for (int j = 0; j < 8; ++j) {
          const int d = seg + j * 16;
          V_lds[d * 72 + row] = h2u(f2h(vf[d]));
        }
      } else {
        int r2 = kvg - hb;
        if (r2 > QL - 1) r2 = QL - 1;
        const size_t base = (size_t)(b * QL + r2) * 12288 + h * HD;
        const ushort_t* kb = qkv + base + HID;
        const ushort_t* vb = qkv + base + 2 * HID;
        *(s16x8*)&K_lds[row * 136 + seg * 8] = *(const s16x8*)(kb + seg * 8);
#pragma unroll
        for (int j = 0; j < 8; ++j) {
          const int d = seg + j * 16;
          V_lds[d * 72 + row] = vb[d];
        }
      }
    }
    __syncthreads();

    f32x4 sa[2][4];
#pragma unroll
    for (int m = 0; m < 2; ++m)
#pragma unroll
      for (int n = 0; n < 4; ++n) sa[m][n] = (f32x4){0.f, 0.f, 0.f, 0.f};
#pragma unroll
    for (int kd = 0; kd < 4; ++kd) {
      f16x8 kf[4];
#pragma unroll
      for (int n = 0; n < 4; ++n)
        kf[n] = *(const f16x8*)&K_lds[(n * 16 + l16) * 136 + kd * 32 + lg * 8];
#pragma unroll
      for (int m = 0; m < 2; ++m)
#pragma unroll
        for (int n = 0; n < 4; ++n)
          sa[m][n] = MFMA16H(qf[m][kd], kf[n], sa[m][n]);
    }

#pragma unroll
    for (int m = 0; m < 2; ++m) {
#pragma unroll
      for (int n = 0; n < 4; ++n) {
        const int kvg = kv0 + n * 16 + l16;
#pragma unroll
        for (int r = 0; r < 4; ++r) {
          const int qg = hb + w * 32 + m * 16 + lg * 4 + r;
          if (kvg > qg) sa[m][n][r] = -1e30f;
        }
      }
      float tm[4], ts[4];
#pragma unroll
      for (int r = 0; r < 4; ++r)
        tm[r] = fmaxf(fmaxf(sa[m][0][r], sa[m][1][r]),
                      fmaxf(sa[m][2][r], sa[m][3][r]));
#pragma unroll
      for (int x = 1; x < 16; x <<= 1)
#pragma unroll
        for (int r = 0; r < 4; ++r)
          tm[r] = fmaxf(tm[r], __shfl_xor(tm[r], x, 16));
#pragma unroll
      for (int r = 0; r < 4; ++r) {
        const float nm = fmaxf(mr[m][r], tm[r]);
        const float corr = __expf(mr[m][r] - nm);
        mr[m][r] = nm;
        sr[m][r] *= corr;
#pragma unroll
        for (int d = 0; d < 8; ++d) o[m][d][r] *= corr;
        ts[r] = 0.f;
      }
#pragma unroll
      for (int n = 0; n < 4; ++n)
#pragma unroll
        for (int r = 0; r < 4; ++r) {
          const float p = __expf(sa[m][n][r] - mr[m][r]);
          sa[m][n][r] = p;
          ts[r] += p;
        }
#pragma unroll
      for (int x = 1; x < 16; x <<= 1)
#pragma unroll
        for (int r = 0; r < 4; ++r) ts[r] += __shfl_xor(ts[r], x, 16);
#pragma unroll
      for (int r = 0; r < 4; ++r) sr[m][r] += ts[r];
#pragma unroll
      for (int n = 0; n < 4; ++n)
#pragma unroll
        for (int r = 0; r < 4; ++r)
          P_lds[(w * 32 + m * 16 + lg * 4 + r) * 72 + n * 16 + l16] =
              h2u(f2h(sa[m][n][r]));
    }

#pragma unroll
    for (int ks = 0; ks < 2; ++ks) {
      f16x8 pa[2];
#pragma unroll
      for (int m = 0; m < 2; ++m)
        pa[m] = *(const f16x8*)&P_lds[(w * 32 + m * 16 + l16) * 72 + ks * 32 + lg * 8];
#pragma unroll
      for (int d = 0; d < 8; ++d) {
        const f16x8 vb =
            *(const f16x8*)&V_lds[(d * 16 + l16) * 72 + ks * 32 + lg * 8];
#pragma unroll
        for (int m = 0; m < 2; ++m) o[m][d] = MFMA16H(pa[m], vb, o[m][d]);
      }
    }
  }

  // epilogue: write directly in MFMA-tiled layout [rb][kb][lane][8]
  // element (row_tok, col=h*128+d*16+l16): lane=(row&15)|(seg<<4), slot=col&7
#pragma unroll
  for (int m = 0; m < 2; ++m) {
    const int rb = b * 16 + w * 2 + m;  // row-block index (of 128 total K32)
#pragma unroll
    for (int r = 0; r < 4; ++r) {
      const float inv = 1.0f / sr[m][r];
#pragma unroll
      for (int d = 0; d < 8; ++d) {
        const int kb = h * 4 + (d >> 1);
        const int lane_dst = (lg * 4 + r) | ((((d & 1) << 1) | (l16 >> 3)) << 4);
        attn_t[((size_t)(rb * 128 + kb)) * 512 + lane_dst * 8 + (l16 & 7)] =
            h2u(f2h(o[m][d][r] * inv));
      }
    }
  }
}

// ---------------------------------------------------------------------------
extern "C" void kernel_launch(void* const* d_in, const int* in_sizes, int n_in,
                              void* d_out, int out_size, void* d_ws,
                              size_t ws_size, hipStream_t stream) {
  const float* hidden   = (const float*)d_in[0];
  const float* c_attn_w = (const float*)d_in[1];
  const float* c_attn_b = (const float*)d_in[2];
  const float* c_proj_w = (const float*)d_in[3];
  const float* k_cache  = (const float*)d_in[4];
  const float* v_cache  = (const float*)d_in[5];
  const int* hist       = (const int*)d_in[6];
  const int* bofs       = (const int*)d_in[7];
  float* out = (float*)d_out;

  char* ws = (char*)d_ws;
  const size_t MB = 1ull << 20;
  ushort_t* w_attn_t = (ushort_t*)(ws);            // 96MB, dead after qkv GEMM
  ushort_t* wproj_t  = (ushort_t*)(ws);            // 32MB, lives after
  ushort_t* qkv_h   = (ushort_t*)(ws + 100 * MB);  // 48MB, live thru attn
  ushort_t* attn_t  = (ushort_t*)(ws + 148 * MB);  // 16MB tiled attn out
  ushort_t* x_t     = (ushort_t*)(ws + 196 * MB);  // 16MB tiled x

  // 1) tile-convert inputs for qkv GEMM
  conv_tile<<<4096, 256, 0, stream>>>(hidden, x_t, 4096, 16384);
  conv_tile<<<24576, 256, 0, stream>>>(c_attn_w, w_attn_t, 4096, 98304);
  // 2) qkv = x @ c_attn_w^T + b : 8 x 96 = 768 blocks
  gemm_t<1, 0, 128><<<768, 512, 73728, stream>>>(x_t, w_attn_t, c_attn_b,
                                                 qkv_h, nullptr, 12288);
  // 3) rope in place (q,k halves)
  rope_inplace<<<2048, 256, 0, stream>>>(qkv_h, hist);
  // 4) tile-convert proj weights (overwrites w_attn region; stream-ordered)
  conv_tile<<<8192, 256, 0, stream>>>(c_proj_w, wproj_t, 4096, 32768);
  // 5) attention -> attn_t (tiled direct)
  attn_fwd<<<256, 512, 0, stream>>>(qkv_h, k_cache, v_cache, hist, bofs,
                                    attn_t);
  // 6) out = attn @ c_proj_w^T : 8 x 32 = 256 blocks
  gemm_t<0, 1, 128><<<256, 512, 73728, stream>>>(attn_t, wproj_t, nullptr,
                                                 nullptr, out, 4096);
}